// Round 4
// baseline (259.489 us; speedup 1.0000x reference)
//
#include <hip/hip_runtime.h>

// AI4Urban fused CFD timestep on 128^3 f32 grid.
// Round 4: coarse-owned (8x2x2) residual/bdiv kernels (8 load-instr/point),
// plane-phased gathers for ILP, QALIAS predictor, rcp hoisting.

#define NN 128
#define NF (NN*NN*NN)   // 2097152

// ---------- row prep ----------

__device__ __forceinline__ void prep9(int z, int y, int rb[9], bool rn[9]) {
  int zi[3] = {z > 0 ? z-1 : 0, z, z < NN-1 ? z+1 : NN-1};
  int yi[3] = {y > 0 ? y-1 : 0, y, y < NN-1 ? y+1 : NN-1};
  bool zo[3] = {z == 0, false, z == NN-1};
  bool yo[3] = {y == 0, false, y == NN-1};
#pragma unroll
  for (int a = 0; a < 3; ++a)
#pragma unroll
    for (int b = 0; b < 3; ++b) {
      rb[a*3+b] = (zi[a]*NN + yi[b])*NN;
      rn[a*3+b] = zo[a] | yo[b];
    }
}

// Plane-phased x-quad stencil: per z-plane, issue all 9 loads, then FMA.
template<bool NEG, int NSET>
__device__ __forceinline__ void sten_phased(
    const float* __restrict__ f, const int rb[9], const bool rn[9],
    bool lo, bool hi, int x0, const float* const Ws[NSET],
    float acc[][4], float4* center) {
#pragma unroll
  for (int a = 0; a < 3; ++a) {
    float t[3][6];
#pragma unroll
    for (int b = 0; b < 3; ++b) {
      int r = a*3 + b;
      int base = rb[r] + x0;
      float4 c = *(const float4*)(f + base);
      float m1 = f[base - (lo ? 0 : 1)];
      float p4 = f[base + (hi ? 3 : 4)];
      if (NEG) {
        float sr = rn[r] ? -1.f : 1.f;
        m1 *= (rn[r] | lo) ? -1.f : 1.f;
        p4 *= (rn[r] | hi) ? -1.f : 1.f;
        c.x *= sr; c.y *= sr; c.z *= sr; c.w *= sr;
      }
      t[b][0]=m1; t[b][1]=c.x; t[b][2]=c.y; t[b][3]=c.z; t[b][4]=c.w; t[b][5]=p4;
    }
    if (a == 1 && center) *center = make_float4(t[1][1], t[1][2], t[1][3], t[1][4]);
#pragma unroll
    for (int b = 0; b < 3; ++b)
#pragma unroll
      for (int s = 0; s < NSET; ++s) {
        const float* W = Ws[s];
        float a0 = W[(a*3+b)*3+0], a1 = W[(a*3+b)*3+1], a2 = W[(a*3+b)*3+2];
#pragma unroll
        for (int k = 0; k < 4; ++k)
          acc[s][k] = fmaf(a0, t[b][k], fmaf(a1, t[b][k+1], fmaf(a2, t[b][k+2], acc[s][k])));
      }
  }
}

// ---------- kernels ----------

__global__ void __launch_bounds__(256) k_solid3(
    float* __restrict__ du, float* __restrict__ dv, float* __restrict__ dw,
    const float* __restrict__ su, const float* __restrict__ sv, const float* __restrict__ sw,
    const float* __restrict__ sg, const float* __restrict__ dtp) {
  int i = blockIdx.x*256 + threadIdx.x;
  if (i >= NF/4) return;
  float dt = dtp[0];
  float4 s4 = ((const float4*)sg)[i];
  float4 a4 = ((const float4*)su)[i];
  float4 b4 = ((const float4*)sv)[i];
  float4 c4 = ((const float4*)sw)[i];
  float4 r4 = make_float4(1.f/(1.f + dt*s4.x), 1.f/(1.f + dt*s4.y),
                          1.f/(1.f + dt*s4.z), 1.f/(1.f + dt*s4.w));
  ((float4*)du)[i] = make_float4(a4.x*r4.x, a4.y*r4.y, a4.z*r4.z, a4.w*r4.w);
  ((float4*)dv)[i] = make_float4(b4.x*r4.x, b4.y*r4.y, b4.z*r4.z, b4.w*r4.w);
  ((float4*)dw)[i] = make_float4(c4.x*r4.x, c4.y*r4.y, c4.z*r4.z, c4.w*r4.w);
}

// Fused momentum for u,v,w; 4 outputs per thread (x-quad).
// QALIAS: qbase fields identical to stencil fields (predictor call).
template<bool QALIAS>
__global__ void __launch_bounds__(256) k_mom3(
    float* __restrict__ du, float* __restrict__ dv, float* __restrict__ dw,
    const float* __restrict__ su, const float* __restrict__ sv, const float* __restrict__ sw,
    const float* __restrict__ qu, const float* __restrict__ qv, const float* __restrict__ qw,
    const float* __restrict__ pf, const float* __restrict__ sg,
    const float* __restrict__ wx, const float* __restrict__ wy,
    const float* __restrict__ wz, const float* __restrict__ wd,
    const float* __restrict__ dtp, float scale) {
  int x0 = threadIdx.x * 4;
  int y  = blockIdx.y * 8 + threadIdx.y;
  int z  = blockIdx.x;
  bool lo = (x0 == 0), hi = (x0 == NN-4);
  int rb[9]; bool rn[9];
  prep9(z, y, rb, rn);
  float dt = dtp[0];
  const float* Wv[4] = {wx, wy, wz, wd};
  const float* Wp[3] = {wx, wy, wz};

  float aU[4][4] = {}, aV[4][4] = {}, aW[4][4] = {}, aP[3][4] = {};
  float4 uc, vc, wc;
  sten_phased<true , 4>(su, rb, rn, lo, hi, x0, Wv, aU, &uc);
  sten_phased<false, 4>(sv, rb, rn, lo, hi, x0, Wv, aV, &vc);
  sten_phased<false, 4>(sw, rb, rn, lo, hi, x0, Wv, aW, &wc);
  sten_phased<false, 3>(pf, rb, rn, lo, hi, x0, Wp, aP, (float4*)nullptr);

  float sw27 = 0.f;
#pragma unroll
  for (int j = 0; j < 27; ++j) sw27 += wd[j];

  int i4 = ((z*NN + y)*NN + x0) >> 2;
  float4 sg4 = ((const float4*)sg)[i4];
  float ucv[4] = {uc.x, uc.y, uc.z, uc.w};
  float vcv[4] = {vc.x, vc.y, vc.z, vc.w};
  float wcv[4] = {wc.x, wc.y, wc.z, wc.w};
  float qua[4], qva[4], qwa[4];
  if (QALIAS) {
#pragma unroll
    for (int k = 0; k < 4; ++k) { qua[k]=ucv[k]; qva[k]=vcv[k]; qwa[k]=wcv[k]; }
  } else {
    float4 qu4 = ((const float4*)qu)[i4];
    float4 qv4 = ((const float4*)qv)[i4];
    float4 qw4 = ((const float4*)qw)[i4];
    qua[0]=qu4.x; qua[1]=qu4.y; qua[2]=qu4.z; qua[3]=qu4.w;
    qva[0]=qv4.x; qva[1]=qv4.y; qva[2]=qv4.z; qva[3]=qv4.w;
    qwa[0]=qw4.x; qwa[1]=qw4.y; qwa[2]=qw4.z; qwa[3]=qw4.w;
  }
  float sga[4] = {sg4.x, sg4.y, sg4.z, sg4.w};
  float ou[4], ov[4], ow[4];
#pragma unroll
  for (int k = 0; k < 4; ++k) {
    float ku = aU[3][k] - 0.5f*sw27*ucv[k];
    float kv = aV[3][k] - 0.5f*sw27*vcv[k];
    float kw = aW[3][k] - 0.5f*sw27*wcv[k];
    float ru = qua[k] + scale*dt*(0.001f*ku - ucv[k]*aU[0][k] - vcv[k]*aU[1][k] - wcv[k]*aU[2][k]) - aP[0][k]*dt;
    float rv = qva[k] + scale*dt*(0.001f*kv - ucv[k]*aV[0][k] - vcv[k]*aV[1][k] - wcv[k]*aV[2][k]) - aP[1][k]*dt;
    float rw = qwa[k] + scale*dt*(0.001f*kw - ucv[k]*aW[0][k] - vcv[k]*aW[1][k] - wcv[k]*aW[2][k]) - aP[2][k]*dt;
    float rd = 1.0f / (1.0f + dt*sga[k]);
    ou[k] = ru*rd; ov[k] = rv*rd; ow[k] = rw*rd;
  }
  ((float4*)du)[i4] = make_float4(ou[0], ou[1], ou[2], ou[3]);
  ((float4*)dv)[i4] = make_float4(ov[0], ov[1], ov[2], ov[3]);
  ((float4*)dw)[i4] = make_float4(ow[0], ow[1], ow[2], ow[3]);
}

// ---------- coarse-owned kernels: thread computes an 8x(2y)x(2z) fine block ----------

// Accumulate one field's 27-tap conv over the fine block into acc[dz][oy][k].
template<bool NEG>
__device__ __forceinline__ void cc_field(
    const float* __restrict__ f, const float* __restrict__ W,
    const int rb16[16], const bool zn[4], const bool yn[4],
    bool lo, bool hi, int fx0, float acc[2][2][8]) {
#pragma unroll
  for (int zp = 0; zp < 4; ++zp) {
    float t[4][10];
#pragma unroll
    for (int yp = 0; yp < 4; ++yp) {
      int base = rb16[zp*4+yp] + fx0;
      float4 A = *(const float4*)(f + base);
      float4 B = *(const float4*)(f + base + 4);
      float m1 = f[base - (lo ? 0 : 1)];
      float p8 = f[base + (hi ? 7 : 8)];
      float* tr = t[yp];
      tr[0]=m1; tr[1]=A.x; tr[2]=A.y; tr[3]=A.z; tr[4]=A.w;
      tr[5]=B.x; tr[6]=B.y; tr[7]=B.z; tr[8]=B.w; tr[9]=p8;
      if (NEG) {
        bool rno = zn[zp] | yn[yp];
        float sr = rno ? -1.f : 1.f;
#pragma unroll
        for (int q = 1; q <= 8; ++q) tr[q] *= sr;
        tr[0] *= (rno | lo) ? -1.f : 1.f;
        tr[9] *= (rno | hi) ? -1.f : 1.f;
      }
    }
#pragma unroll
    for (int dz = 0; dz < 2; ++dz) {
      int a = zp - dz;
      if (a < 0 || a > 2) continue;
#pragma unroll
      for (int oy = 0; oy < 2; ++oy)
#pragma unroll
        for (int b = 0; b < 3; ++b) {
          const float* tr = t[oy + b];
          float w0 = W[(a*3+b)*3+0], w1 = W[(a*3+b)*3+1], w2 = W[(a*3+b)*3+2];
#pragma unroll
          for (int k = 0; k < 8; ++k)
            acc[dz][oy][k] = fmaf(w0, tr[k], fmaf(w1, tr[k+1], fmaf(w2, tr[k+2], acc[dz][oy][k])));
        }
    }
  }
}

__device__ __forceinline__ void cc_prep(int Z, int Y, int rb16[16], bool zn[4], bool yn[4]) {
  int fz[4] = {2*Z > 0 ? 2*Z-1 : 0, 2*Z, 2*Z+1, 2*Z+2 < NN ? 2*Z+2 : NN-1};
  int fy[4] = {2*Y > 0 ? 2*Y-1 : 0, 2*Y, 2*Y+1, 2*Y+2 < NN ? 2*Y+2 : NN-1};
  zn[0] = (Z == 0); zn[1] = zn[2] = false; zn[3] = (Z == 63);
  yn[0] = (Y == 0); yn[1] = yn[2] = false; yn[3] = (Y == 63);
#pragma unroll
  for (int a = 0; a < 4; ++a)
#pragma unroll
    for (int b = 0; b < 4; ++b)
      rb16[a*4+b] = (fz[a]*NN + fy[b])*NN;
}

// it0: b = -(div)/dt, rfine = A(p0)-b, rc1 = restrict(rfine). 65536 threads.
__global__ void __launch_bounds__(256) k_bdivres(
    float* __restrict__ bb, float* __restrict__ rfine, float* __restrict__ rc1,
    const float* __restrict__ su, const float* __restrict__ sv, const float* __restrict__ sw,
    const float* __restrict__ pf,
    const float* __restrict__ wx, const float* __restrict__ wy, const float* __restrict__ wz,
    const float* __restrict__ wA, const float* __restrict__ wr,
    const float* __restrict__ dtp) {
  int i = blockIdx.x*256 + threadIdx.x;
  int Xq = i & 15, Y = (i >> 4) & 63, Z = i >> 10;
  int fx0 = Xq*8;
  bool lo = (Xq == 0), hi = (Xq == 15);
  int rb16[16]; bool zn[4], yn[4];
  cc_prep(Z, Y, rb16, zn, yn);

  float bs[2][2][8] = {}, ap[2][2][8] = {};
  cc_field<true >(su, wx, rb16, zn, yn, lo, hi, fx0, bs);
  cc_field<false>(sv, wy, rb16, zn, yn, lo, hi, fx0, bs);
  cc_field<false>(sw, wz, rb16, zn, yn, lo, hi, fx0, bs);
  cc_field<false>(pf, wA, rb16, zn, yn, lo, hi, fx0, ap);

  float rdt = 1.0f / dtp[0];
  float rs[4] = {};
#pragma unroll
  for (int dz = 0; dz < 2; ++dz)
#pragma unroll
    for (int oy = 0; oy < 2; ++oy) {
      int fi = ((2*Z+dz)*NN + 2*Y+oy)*NN + fx0;
      float bv[8], rv[8];
#pragma unroll
      for (int k = 0; k < 8; ++k) {
        bv[k] = -bs[dz][oy][k]*rdt;
        rv[k] = ap[dz][oy][k] - bv[k];
      }
      *(float4*)(bb+fi)      = make_float4(bv[0],bv[1],bv[2],bv[3]);
      *(float4*)(bb+fi+4)    = make_float4(bv[4],bv[5],bv[6],bv[7]);
      *(float4*)(rfine+fi)   = make_float4(rv[0],rv[1],rv[2],rv[3]);
      *(float4*)(rfine+fi+4) = make_float4(rv[4],rv[5],rv[6],rv[7]);
#pragma unroll
      for (int cq = 0; cq < 4; ++cq)
#pragma unroll
        for (int dx = 0; dx < 2; ++dx)
          rs[cq] = fmaf(wr[(dz*2+oy)*2+dx], rv[2*cq+dx], rs[cq]);
    }
  *(float4*)(rc1 + ((size_t)(Z*64+Y)*64 + Xq*4)) = make_float4(rs[0],rs[1],rs[2],rs[3]);
}

// it1: rfine = A(pbuf)-b (b read back), rc1 = restrict(rfine).
__global__ void __launch_bounds__(256) k_resres1(
    float* __restrict__ rfine, float* __restrict__ rc1,
    const float* __restrict__ pf, const float* __restrict__ bb,
    const float* __restrict__ wA, const float* __restrict__ wr) {
  int i = blockIdx.x*256 + threadIdx.x;
  int Xq = i & 15, Y = (i >> 4) & 63, Z = i >> 10;
  int fx0 = Xq*8;
  bool lo = (Xq == 0), hi = (Xq == 15);
  int rb16[16]; bool zn[4], yn[4];
  cc_prep(Z, Y, rb16, zn, yn);

  float ap[2][2][8] = {};
  cc_field<false>(pf, wA, rb16, zn, yn, lo, hi, fx0, ap);

  float rs[4] = {};
#pragma unroll
  for (int dz = 0; dz < 2; ++dz)
#pragma unroll
    for (int oy = 0; oy < 2; ++oy) {
      int fi = ((2*Z+dz)*NN + 2*Y+oy)*NN + fx0;
      float4 b0 = *(const float4*)(bb+fi);
      float4 b1 = *(const float4*)(bb+fi+4);
      float bv[8] = {b0.x,b0.y,b0.z,b0.w,b1.x,b1.y,b1.z,b1.w};
      float rv[8];
#pragma unroll
      for (int k = 0; k < 8; ++k) rv[k] = ap[dz][oy][k] - bv[k];
      *(float4*)(rfine+fi)   = make_float4(rv[0],rv[1],rv[2],rv[3]);
      *(float4*)(rfine+fi+4) = make_float4(rv[4],rv[5],rv[6],rv[7]);
#pragma unroll
      for (int cq = 0; cq < 4; ++cq)
#pragma unroll
        for (int dx = 0; dx < 2; ++dx)
          rs[cq] = fmaf(wr[(dz*2+oy)*2+dx], rv[2*cq+dx], rs[cq]);
    }
  *(float4*)(rc1 + ((size_t)(Z*64+Y)*64 + Xq*4)) = make_float4(rs[0],rs[1],rs[2],rs[3]);
}

// Generic 2x2x2 stride-2 restriction.
__global__ void __launch_bounds__(256) k_restrict(
    float* __restrict__ dst, const float* __restrict__ src,
    const float* __restrict__ wr, int no) {
  int i = blockIdx.x*256 + threadIdx.x;
  int n3 = no*no*no;
  if (i >= n3) return;
  int x = i % no; int t = i / no; int y = t % no; int z = t / no;
  int ni = 2*no;
  float s = 0.f;
#pragma unroll
  for (int a = 0; a < 2; ++a)
#pragma unroll
    for (int b = 0; b < 2; ++b)
#pragma unroll
      for (int c = 0; c < 2; ++c)
        s = fmaf(wr[(a*2+b)*2+c], src[((2*z+a)*ni + (2*y+b))*ni + (2*x+c)], s);
  dst[i] = s;
}

// Zero-boundary conv of implicit prolongation.
__device__ __forceinline__ float azb_prol(const float* __restrict__ wh, int hs, int s,
    int z, int y, int x, const float* __restrict__ wA) {
  float acc = 0.f;
#pragma unroll
  for (int a = 0; a < 3; ++a) { int zz = z + a - 1; if ((unsigned)zz >= (unsigned)s) continue;
#pragma unroll
    for (int b = 0; b < 3; ++b) { int yy = y + b - 1; if ((unsigned)yy >= (unsigned)s) continue;
#pragma unroll
      for (int c = 0; c < 3; ++c) { int xx = x + c - 1; if ((unsigned)xx >= (unsigned)s) continue;
        acc = fmaf(wA[(a*3+b)*3+c], wh[((zz>>1)*hs + (yy>>1))*hs + (xx>>1)], acc);
      } } }
  return acc;
}

// Single-block MG core: restrict 32^3 down to 1^3, up-sweep to w16.
__global__ void __launch_bounds__(512) k_mg_small(
    float* __restrict__ w16, float* __restrict__ r_o,
    const float* __restrict__ rc2,
    const float* __restrict__ wA, const float* __restrict__ wr) {
  __shared__ float r16[4096];
  __shared__ float r8[512];
  __shared__ float r4[64];
  __shared__ float r2[8];
  __shared__ float wa[512];
  __shared__ float wb[64];
  __shared__ float scal[2];
  int tid = threadIdx.x;
  float diag = wA[13];
  float wrl[8];
#pragma unroll
  for (int j = 0; j < 8; ++j) wrl[j] = wr[j];

  for (int j = tid; j < 4096; j += 512) {
    int x = j & 15, y = (j >> 4) & 15, z = j >> 8;
    float s = 0.f;
#pragma unroll
    for (int a = 0; a < 2; ++a)
#pragma unroll
      for (int b = 0; b < 2; ++b)
#pragma unroll
        for (int c = 0; c < 2; ++c)
          s = fmaf(wrl[(a*2+b)*2+c], rc2[((2*z+a)*32 + (2*y+b))*32 + (2*x+c)], s);
    r16[j] = s;
  }
  __syncthreads();
  {
    int j = tid;
    int x = j & 7, y = (j >> 3) & 7, z = j >> 6;
    float s = 0.f;
#pragma unroll
    for (int a = 0; a < 2; ++a)
#pragma unroll
      for (int b = 0; b < 2; ++b)
#pragma unroll
        for (int c = 0; c < 2; ++c)
          s = fmaf(wrl[(a*2+b)*2+c], r16[((2*z+a)*16 + (2*y+b))*16 + (2*x+c)], s);
    r8[j] = s;
  }
  __syncthreads();
  if (tid < 64) {
    int x = tid & 3, y = (tid >> 2) & 3, z = tid >> 4;
    float s = 0.f;
#pragma unroll
    for (int a = 0; a < 2; ++a)
#pragma unroll
      for (int b = 0; b < 2; ++b)
#pragma unroll
        for (int c = 0; c < 2; ++c)
          s = fmaf(wrl[(a*2+b)*2+c], r8[((2*z+a)*8 + (2*y+b))*8 + (2*x+c)], s);
    r4[tid] = s;
  }
  __syncthreads();
  if (tid < 8) {
    int x = tid & 1, y = (tid >> 1) & 1, z = tid >> 2;
    float s = 0.f;
#pragma unroll
    for (int a = 0; a < 2; ++a)
#pragma unroll
      for (int b = 0; b < 2; ++b)
#pragma unroll
        for (int c = 0; c < 2; ++c)
          s = fmaf(wrl[(a*2+b)*2+c], r4[((2*z+a)*4 + (2*y+b))*4 + (2*x+c)], s);
    r2[tid] = s;
  }
  __syncthreads();
  if (tid == 0) {
    float s = 0.f;
#pragma unroll
    for (int j = 0; j < 8; ++j) s = fmaf(wrl[j], r2[j], s);
    scal[0] = s;
    r_o[0] = s;
    scal[1] = s / diag;
  }
  __syncthreads();
  if (tid < 8) {
    int x = tid & 1, y = (tid >> 1) & 1, z = tid >> 2;
    float wp = scal[1];
    float az = azb_prol(&scal[1], 1, 2, z, y, x, wA);
    wa[tid] = wp - az/diag + r2[tid]/diag;
  }
  __syncthreads();
  if (tid < 64) {
    int x = tid & 3, y = (tid >> 2) & 3, z = tid >> 4;
    float wp = wa[((z>>1)*2 + (y>>1))*2 + (x>>1)];
    float az = azb_prol(wa, 2, 4, z, y, x, wA);
    wb[tid] = wp - az/diag + r4[tid]/diag;
  }
  __syncthreads();
  {
    int j = tid;
    int x = j & 7, y = (j >> 3) & 7, z = j >> 6;
    float wp = wb[((z>>1)*4 + (y>>1))*4 + (x>>1)];
    float az = azb_prol(wb, 4, 8, z, y, x, wA);
    wa[j] = wp - az/diag + r8[j]/diag;
  }
  __syncthreads();
  for (int j = tid; j < 4096; j += 512) {
    int x = j & 15, y = (j >> 4) & 15, z = j >> 8;
    float wp = wa[((z>>1)*8 + (y>>1))*8 + (x>>1)];
    float az = azb_prol(wa, 8, 16, z, y, x, wA);
    w16[j] = wp - az/diag + r16[j]/diag;
  }
}

__global__ void __launch_bounds__(256) k_coarse_step(
    float* __restrict__ wout, const float* __restrict__ wh,
    const float* __restrict__ rl, const float* __restrict__ wA, int s) {
  int i = blockIdx.x*256 + threadIdx.x;
  int n3 = s*s*s;
  if (i >= n3) return;
  int x = i % s; int t = i / s; int y = t % s; int z = t / s;
  int hs = s >> 1;
  float diag = wA[13];
  float wp = wh[((z>>1)*hs + (y>>1))*hs + (x>>1)];
  float az = azb_prol(wh, hs, s, z, y, x, wA);
  wout[i] = wp - az/diag + rl[i]/diag;
}

// Pointwise p update: pdst = psrc - w64[parent] - rfine/diag.
__global__ void __launch_bounds__(256) k_pupd4(
    float* __restrict__ pdst, float* __restrict__ wmgo,
    const float* __restrict__ psrc, const float* __restrict__ rfine,
    const float* __restrict__ w64, const float* __restrict__ wA, int writeWmg) {
  int i4 = blockIdx.x*256 + threadIdx.x;
  if (i4 >= NF/4) return;
  int i = i4*4;
  int x = i & (NN-1); int t = i >> 7; int y = t & (NN-1); int z = t >> 7;
  float rdiag = 1.0f / wA[13];
  float2 w2 = *(const float2*)(w64 + ((size_t)(z>>1)*64 + (y>>1))*64 + (x>>1));
  float4 ps = ((const float4*)psrc)[i4];
  float4 rf = ((const float4*)rfine)[i4];
  float4 o = make_float4(ps.x - w2.x - rf.x*rdiag,
                         ps.y - w2.x - rf.y*rdiag,
                         ps.z - w2.y - rf.z*rdiag,
                         ps.w - w2.y - rf.w*rdiag);
  ((float4*)pdst)[i4] = o;
  if (writeWmg) ((float4*)wmgo)[i4] = make_float4(w2.x, w2.x, w2.y, w2.y);
}

// Final projection (x-quad, plane-phased).
__global__ void __launch_bounds__(256) k_proj3(
    float* __restrict__ u, float* __restrict__ v, float* __restrict__ w,
    const float* __restrict__ pf, const float* __restrict__ sg,
    const float* __restrict__ wx, const float* __restrict__ wy,
    const float* __restrict__ wz, const float* __restrict__ dtp) {
  int x0 = threadIdx.x * 4;
  int y  = blockIdx.y * 8 + threadIdx.y;
  int z  = blockIdx.x;
  bool lo = (x0 == 0), hi = (x0 == NN-4);
  int rb[9]; bool rn[9];
  prep9(z, y, rb, rn);
  const float* Wp[3] = {wx, wy, wz};
  float aP[3][4] = {};
  sten_phased<false, 3>(pf, rb, rn, lo, hi, x0, Wp, aP, (float4*)nullptr);
  float dt = dtp[0];
  int i4 = ((z*NN + y)*NN + x0) >> 2;
  float4 u4 = ((const float4*)u)[i4];
  float4 v4 = ((const float4*)v)[i4];
  float4 w4 = ((const float4*)w)[i4];
  float4 sg4 = ((const float4*)sg)[i4];
  float ua[4] = {u4.x, u4.y, u4.z, u4.w};
  float va[4] = {v4.x, v4.y, v4.z, v4.w};
  float wa[4] = {w4.x, w4.y, w4.z, w4.w};
  float sa[4] = {sg4.x, sg4.y, sg4.z, sg4.w};
  float ou[4], ov[4], ow[4];
#pragma unroll
  for (int k = 0; k < 4; ++k) {
    float rd = 1.0f / (1.0f + dt*sa[k]);
    ou[k] = (ua[k] - aP[0][k]*dt)*rd;
    ov[k] = (va[k] - aP[1][k]*dt)*rd;
    ow[k] = (wa[k] - aP[2][k]*dt)*rd;
  }
  ((float4*)u)[i4] = make_float4(ou[0], ou[1], ou[2], ou[3]);
  ((float4*)v)[i4] = make_float4(ov[0], ov[1], ov[2], ov[3]);
  ((float4*)w)[i4] = make_float4(ow[0], ow[1], ow[2], ow[3]);
}

// ---------- launch ----------

extern "C" void kernel_launch(void* const* d_in, const int* in_sizes, int n_in,
                              void* d_out, int out_size, void* d_ws, size_t ws_size,
                              hipStream_t stream) {
  const float* values_u = (const float*)d_in[0];
  const float* values_v = (const float*)d_in[1];
  const float* values_w = (const float*)d_in[2];
  const float* values_p = (const float*)d_in[3];
  const float* sigma    = (const float*)d_in[4];
  const float* wx       = (const float*)d_in[5];
  const float* wy       = (const float*)d_in[6];
  const float* wz       = (const float*)d_in[7];
  const float* wd       = (const float*)d_in[8];
  const float* wA       = (const float*)d_in[9];
  const float* wr       = (const float*)d_in[10];
  const float* dtp      = (const float*)d_in[11];

  float* out   = (float*)d_out;
  float* u_o   = out;
  float* v_o   = out + (size_t)NF;
  float* w_o   = out + (size_t)2*NF;
  float* p_o   = out + (size_t)3*NF;
  float* wmg_o = out + (size_t)4*NF;
  float* r_o   = out + (size_t)5*NF;

  float* ws    = (float*)d_ws;
  float* f0    = ws;                     // b_u
  float* f1    = f0 + (size_t)NF;        // b_v
  float* f2    = f1 + (size_t)NF;        // b_w
  float* bws   = f2 + (size_t)NF;        // b
  float* rfine = bws + (size_t)NF;       // A(pp)-b
  float* pbuf  = rfine + (size_t)NF;     // p after iter 0
  float* rc1   = pbuf + (size_t)NF;      // 64^3
  float* rc2   = rc1 + 262144;           // 32^3
  float* w16   = rc2 + 32768;            // 16^3
  float* w32   = w16 + 4096;             // 32^3
  float* w64   = w32 + 32768;            // 64^3

  const int TB = 256;
  dim3 blkS(32, 8, 1);
  dim3 grdS(128, 16, 1);

  // momentum chain
  k_solid3<<<NF/4/TB, TB, 0, stream>>>(u_o, v_o, w_o, values_u, values_v, values_w, sigma, dtp);
  k_mom3<true ><<<grdS, blkS, 0, stream>>>(f0, f1, f2, u_o, v_o, w_o, u_o, v_o, w_o,
                                           values_p, sigma, wx, wy, wz, wd, dtp, 0.5f);
  k_mom3<false><<<grdS, blkS, 0, stream>>>(u_o, v_o, w_o, f0, f1, f2, u_o, v_o, w_o,
                                           values_p, sigma, wx, wy, wz, wd, dtp, 1.0f);

  // it 0: fused b + residual + first restriction (coarse-owned)
  k_bdivres<<<256, TB, 0, stream>>>(bws, rfine, rc1, u_o, v_o, w_o, values_p,
                                    wx, wy, wz, wA, wr, dtp);
  k_restrict<<<128, TB, 0, stream>>>(rc2, rc1, wr, 32);
  k_mg_small<<<1, 512, 0, stream>>>(w16, r_o, rc2, wA, wr);
  k_coarse_step<<<128, TB, 0, stream>>>(w32, w16, rc2, wA, 32);
  k_coarse_step<<<1024, TB, 0, stream>>>(w64, w32, rc1, wA, 64);
  k_pupd4<<<NF/4/TB, TB, 0, stream>>>(pbuf, wmg_o, values_p, rfine, w64, wA, 0);

  // it 1
  k_resres1<<<256, TB, 0, stream>>>(rfine, rc1, pbuf, bws, wA, wr);
  k_restrict<<<128, TB, 0, stream>>>(rc2, rc1, wr, 32);
  k_mg_small<<<1, 512, 0, stream>>>(w16, r_o, rc2, wA, wr);
  k_coarse_step<<<128, TB, 0, stream>>>(w32, w16, rc2, wA, 32);
  k_coarse_step<<<1024, TB, 0, stream>>>(w64, w32, rc1, wA, 64);
  k_pupd4<<<NF/4/TB, TB, 0, stream>>>(p_o, wmg_o, pbuf, rfine, w64, wA, 1);

  // final projection
  k_proj3<<<grdS, blkS, 0, stream>>>(u_o, v_o, w_o, p_o, sigma, wx, wy, wz, dtp);
}

// Round 5
// 242.905 us; speedup vs baseline: 1.0683x; 1.0683x over previous
//
#include <hip/hip_runtime.h>

// AI4Urban fused CFD timestep on 128^3 f32 grid.
// Round 5: round-3 structure, ONE change: mom3/proj3 grid order is now
// yband-fastest / z-slowest (plane-major dispatch) so the concurrent block
// window stays within a few adjacent z-planes and the 3x z-halo re-read
// hits L2 (r2's locality) while keeping x-quad instruction economy.

#define NN 128
#define NF (NN*NN*NN)   // 2097152

// ---------- row prep ----------

// Clamped row bases + OOB flags for a 3^3 stencil at (z,y). r = a*3+b.
__device__ __forceinline__ void prep9(int z, int y, int rb[9], bool rn[9]) {
  int zi[3] = {z > 0 ? z-1 : 0, z, z < NN-1 ? z+1 : NN-1};
  int yi[3] = {y > 0 ? y-1 : 0, y, y < NN-1 ? y+1 : NN-1};
  bool zo[3] = {z == 0, false, z == NN-1};
  bool yo[3] = {y == 0, false, y == NN-1};
#pragma unroll
  for (int a = 0; a < 3; ++a)
#pragma unroll
    for (int b = 0; b < 3; ++b) {
      rb[a*3+b] = (zi[a]*NN + yi[b])*NN;
      rn[a*3+b] = zo[a] | yo[b];
    }
}

// ---------- 4-wide stencil helpers (x-quad) ----------

template<bool NEG>
__device__ __forceinline__ void sten_vel(
    const float* __restrict__ f, const int rb[9], const bool rn[9],
    bool lo, bool hi, int x0,
    const float* __restrict__ w0p, const float* __restrict__ w1p,
    const float* __restrict__ w2p, const float* __restrict__ w3p,
    float acc[4][4], float4* center) {
  const float* const Ws[4] = {w0p, w1p, w2p, w3p};
#pragma unroll
  for (int r = 0; r < 9; ++r) {
    int base = rb[r] + x0;
    float4 c = *(const float4*)(f + base);
    float m1 = f[base - (lo ? 0 : 1)];
    float p4 = f[base + (hi ? 3 : 4)];
    if (NEG) {
      float sr = rn[r] ? -1.f : 1.f;
      m1 *= (rn[r] | lo) ? -1.f : 1.f;
      p4 *= (rn[r] | hi) ? -1.f : 1.f;
      c.x *= sr; c.y *= sr; c.z *= sr; c.w *= sr;
    }
    if (r == 4 && center) *center = c;
    float t[6] = {m1, c.x, c.y, c.z, c.w, p4};
#pragma unroll
    for (int s = 0; s < 4; ++s) {
      const float* W = Ws[s];
      float a0 = W[r*3+0], a1 = W[r*3+1], a2 = W[r*3+2];
#pragma unroll
      for (int k = 0; k < 4; ++k)
        acc[s][k] = fmaf(a0, t[k], fmaf(a1, t[k+1], fmaf(a2, t[k+2], acc[s][k])));
    }
  }
}

__device__ __forceinline__ void sten_p3(
    const float* __restrict__ f, const int rb[9], const bool rn[9],
    bool lo, bool hi, int x0,
    const float* __restrict__ w0p, const float* __restrict__ w1p,
    const float* __restrict__ w2p, float acc[3][4]) {
  const float* const Ws[3] = {w0p, w1p, w2p};
#pragma unroll
  for (int r = 0; r < 9; ++r) {
    int base = rb[r] + x0;
    float4 c = *(const float4*)(f + base);
    float m1 = f[base - (lo ? 0 : 1)];
    float p4 = f[base + (hi ? 3 : 4)];
    float t[6] = {m1, c.x, c.y, c.z, c.w, p4};
#pragma unroll
    for (int s = 0; s < 3; ++s) {
      const float* W = Ws[s];
      float a0 = W[r*3+0], a1 = W[r*3+1], a2 = W[r*3+2];
#pragma unroll
      for (int k = 0; k < 4; ++k)
        acc[s][k] = fmaf(a0, t[k], fmaf(a1, t[k+1], fmaf(a2, t[k+2], acc[s][k])));
    }
  }
}

// ---------- kernels ----------

__global__ void __launch_bounds__(256) k_solid3(
    float* __restrict__ du, float* __restrict__ dv, float* __restrict__ dw,
    const float* __restrict__ su, const float* __restrict__ sv, const float* __restrict__ sw,
    const float* __restrict__ sg, const float* __restrict__ dtp) {
  int i = blockIdx.x*256 + threadIdx.x;
  if (i >= NF/4) return;
  float dt = dtp[0];
  float4 s4 = ((const float4*)sg)[i];
  float4 a4 = ((const float4*)su)[i];
  float4 b4 = ((const float4*)sv)[i];
  float4 c4 = ((const float4*)sw)[i];
  float4 d4 = make_float4(1.f + dt*s4.x, 1.f + dt*s4.y, 1.f + dt*s4.z, 1.f + dt*s4.w);
  ((float4*)du)[i] = make_float4(a4.x/d4.x, a4.y/d4.y, a4.z/d4.z, a4.w/d4.w);
  ((float4*)dv)[i] = make_float4(b4.x/d4.x, b4.y/d4.y, b4.z/d4.z, b4.w/d4.w);
  ((float4*)dw)[i] = make_float4(c4.x/d4.x, c4.y/d4.y, c4.z/d4.z, c4.w/d4.w);
}

// Fused momentum for u,v,w; 4 outputs per thread (x-quad).
// Grid: (yband=16, z=128) — plane-major dispatch for L2 z-reuse.
__global__ void __launch_bounds__(256) k_mom3(
    float* __restrict__ du, float* __restrict__ dv, float* __restrict__ dw,
    const float* __restrict__ su, const float* __restrict__ sv, const float* __restrict__ sw,
    const float* __restrict__ qu, const float* __restrict__ qv, const float* __restrict__ qw,
    const float* __restrict__ pf, const float* __restrict__ sg,
    const float* __restrict__ wx, const float* __restrict__ wy,
    const float* __restrict__ wz, const float* __restrict__ wd,
    const float* __restrict__ dtp, float scale) {
  int x0 = threadIdx.x * 4;
  int y  = blockIdx.x * 8 + threadIdx.y;   // yband fastest
  int z  = blockIdx.y;                      // z slowest
  bool lo = (x0 == 0), hi = (x0 == NN-4);
  int rb[9]; bool rn[9];
  prep9(z, y, rb, rn);
  float dt = dtp[0];

  float aU[4][4] = {}, aV[4][4] = {}, aW[4][4] = {}, aP[3][4] = {};
  float4 uc, vc, wc;
  sten_vel<true >(su, rb, rn, lo, hi, x0, wx, wy, wz, wd, aU, &uc);
  sten_vel<false>(sv, rb, rn, lo, hi, x0, wx, wy, wz, wd, aV, &vc);
  sten_vel<false>(sw, rb, rn, lo, hi, x0, wx, wy, wz, wd, aW, &wc);
  sten_p3(pf, rb, rn, lo, hi, x0, wx, wy, wz, aP);

  float sw27 = 0.f;
#pragma unroll
  for (int j = 0; j < 27; ++j) sw27 += wd[j];

  int i4 = ((z*NN + y)*NN + x0) >> 2;
  float4 qu4 = ((const float4*)qu)[i4];
  float4 qv4 = ((const float4*)qv)[i4];
  float4 qw4 = ((const float4*)qw)[i4];
  float4 sg4 = ((const float4*)sg)[i4];
  float ucv[4] = {uc.x, uc.y, uc.z, uc.w};
  float vcv[4] = {vc.x, vc.y, vc.z, vc.w};
  float wcv[4] = {wc.x, wc.y, wc.z, wc.w};
  float qua[4] = {qu4.x, qu4.y, qu4.z, qu4.w};
  float qva[4] = {qv4.x, qv4.y, qv4.z, qv4.w};
  float qwa[4] = {qw4.x, qw4.y, qw4.z, qw4.w};
  float sga[4] = {sg4.x, sg4.y, sg4.z, sg4.w};
  float ou[4], ov[4], ow[4];
#pragma unroll
  for (int k = 0; k < 4; ++k) {
    float ku = aU[3][k] - 0.5f*sw27*ucv[k];
    float kv = aV[3][k] - 0.5f*sw27*vcv[k];
    float kw = aW[3][k] - 0.5f*sw27*wcv[k];
    float ru = qua[k] + scale*dt*(0.001f*ku - ucv[k]*aU[0][k] - vcv[k]*aU[1][k] - wcv[k]*aU[2][k]) - aP[0][k]*dt;
    float rv = qva[k] + scale*dt*(0.001f*kv - ucv[k]*aV[0][k] - vcv[k]*aV[1][k] - wcv[k]*aV[2][k]) - aP[1][k]*dt;
    float rw = qwa[k] + scale*dt*(0.001f*kw - ucv[k]*aW[0][k] - vcv[k]*aW[1][k] - wcv[k]*aW[2][k]) - aP[2][k]*dt;
    float d = 1.0f + dt*sga[k];
    ou[k] = ru/d; ov[k] = rv/d; ow[k] = rw/d;
  }
  ((float4*)du)[i4] = make_float4(ou[0], ou[1], ou[2], ou[3]);
  ((float4*)dv)[i4] = make_float4(ov[0], ov[1], ov[2], ov[3]);
  ((float4*)dw)[i4] = make_float4(ow[0], ow[1], ow[2], ow[3]);
}

// ---------- coarse-cell fused kernels (2x2x2 fine ownership) ----------

__device__ __forceinline__ void row4(const float* __restrict__ f, int base,
                                     bool lo, bool hi, float t[4]) {
  float2 c = *(const float2*)(f + base);
  t[0] = f[base - (lo ? 0 : 1)];
  t[1] = c.x; t[2] = c.y;
  t[3] = f[base + (hi ? 1 : 2)];
}

__device__ __forceinline__ void prep16(int Z, int Y, int rb[16], bool rn[16]) {
  int z0 = 2*Z, y0 = 2*Y;
  int zi[4] = {z0 > 0 ? z0-1 : 0, z0, z0+1, z0+2 < NN ? z0+2 : NN-1};
  int yi[4] = {y0 > 0 ? y0-1 : 0, y0, y0+1, y0+2 < NN ? y0+2 : NN-1};
  bool zo[4] = {Z == 0, false, false, Z == 63};
  bool yo[4] = {Y == 0, false, false, Y == 63};
#pragma unroll
  for (int a = 0; a < 4; ++a)
#pragma unroll
    for (int b = 0; b < 4; ++b) {
      rb[a*4+b] = (zi[a]*NN + yi[b])*NN;
      rn[a*4+b] = zo[a] | yo[b];
    }
}

template<bool NEG>
__device__ __forceinline__ void load16(const float* __restrict__ f,
    const int rb[16], const bool rn[16], bool lo, bool hi, int x0, float t[16][4]) {
#pragma unroll
  for (int r = 0; r < 16; ++r) {
    row4(f, rb[r] + x0, lo, hi, t[r]);
    if (NEG) {
      float sr = rn[r] ? -1.f : 1.f;
      t[r][0] *= (rn[r] | lo) ? -1.f : 1.f;
      t[r][3] *= (rn[r] | hi) ? -1.f : 1.f;
      t[r][1] *= sr; t[r][2] *= sr;
    }
  }
}

__device__ __forceinline__ void dots8(const float t[16][4],
                                      const float* __restrict__ W, float s8[8]) {
#pragma unroll
  for (int dz = 0; dz < 2; ++dz)
#pragma unroll
    for (int dy = 0; dy < 2; ++dy)
#pragma unroll
      for (int dx = 0; dx < 2; ++dx) {
        float s = 0.f;
#pragma unroll
        for (int a = 0; a < 3; ++a)
#pragma unroll
          for (int b = 0; b < 3; ++b)
#pragma unroll
            for (int c = 0; c < 3; ++c)
              s = fmaf(W[(a*3+b)*3+c], t[(dz+a)*4 + dy+b][dx+c], s);
        s8[(dz*2+dy)*2+dx] += s;
      }
}

// Fused: b = -(xadv(u)+yadv(v)+zadv(w))/dt, rfine = A(p0)-b, rc1 = restrict(rfine).
__global__ void __launch_bounds__(256) k_bdiv_resres(
    float* __restrict__ bb, float* __restrict__ rfine, float* __restrict__ rc1,
    const float* __restrict__ su, const float* __restrict__ sv, const float* __restrict__ sw,
    const float* __restrict__ pf,
    const float* __restrict__ wx, const float* __restrict__ wy, const float* __restrict__ wz,
    const float* __restrict__ wA, const float* __restrict__ wr,
    const float* __restrict__ dtp) {
  int i = blockIdx.x*256 + threadIdx.x;
  if (i >= 64*64*64) return;
  int X = i & 63, Y = (i >> 6) & 63, Z = i >> 12;
  bool lo = (X == 0), hi = (X == 63);
  int x0 = 2*X;
  int rb[16]; bool rn[16];
  prep16(Z, Y, rb, rn);
  float rdt = 1.0f / dtp[0];

  float s8[8] = {};
  {
    float t[16][4];
    load16<true >(su, rb, rn, lo, hi, x0, t); dots8(t, wx, s8);
  }
  {
    float t[16][4];
    load16<false>(sv, rb, rn, lo, hi, x0, t); dots8(t, wy, s8);
  }
  {
    float t[16][4];
    load16<false>(sw, rb, rn, lo, hi, x0, t); dots8(t, wz, s8);
  }
  float a8[8] = {};
  {
    float t[16][4];
    load16<false>(pf, rb, rn, lo, hi, x0, t); dots8(t, wA, a8);
  }
  float rsum = 0.f;
#pragma unroll
  for (int f = 0; f < 8; ++f) {
    int dz = f >> 2, dy = (f >> 1) & 1, dx = f & 1;
    float bcell = -s8[f] * rdt;
    float rcell = a8[f] - bcell;
    int idx = ((2*Z+dz)*NN + (2*Y+dy))*NN + x0 + dx;
    bb[idx] = bcell;
    rfine[idx] = rcell;
    rsum = fmaf(wr[(dz*2+dy)*2+dx], rcell, rsum);
  }
  rc1[i] = rsum;
}

// it>=1 residual: rfine = A(pst) - b, rc1 = restrict(rfine).
__global__ void __launch_bounds__(256) k_resres1(
    float* __restrict__ rfine, float* __restrict__ rc1,
    const float* __restrict__ pf, const float* __restrict__ bb,
    const float* __restrict__ wA, const float* __restrict__ wr) {
  int i = blockIdx.x*256 + threadIdx.x;
  if (i >= 64*64*64) return;
  int X = i & 63, Y = (i >> 6) & 63, Z = i >> 12;
  bool lo = (X == 0), hi = (X == 63);
  int x0 = 2*X;
  int rb[16]; bool rn[16];
  prep16(Z, Y, rb, rn);
  float a8[8] = {};
  {
    float t[16][4];
    load16<false>(pf, rb, rn, lo, hi, x0, t); dots8(t, wA, a8);
  }
  float rsum = 0.f;
#pragma unroll
  for (int f = 0; f < 8; ++f) {
    int dz = f >> 2, dy = (f >> 1) & 1, dx = f & 1;
    int idx = ((2*Z+dz)*NN + (2*Y+dy))*NN + x0 + dx;
    float rcell = a8[f] - bb[idx];
    rfine[idx] = rcell;
    rsum = fmaf(wr[(dz*2+dy)*2+dx], rcell, rsum);
  }
  rc1[i] = rsum;
}

__global__ void __launch_bounds__(256) k_restrict(
    float* __restrict__ dst, const float* __restrict__ src,
    const float* __restrict__ wr, int no) {
  int i = blockIdx.x*256 + threadIdx.x;
  int n3 = no*no*no;
  if (i >= n3) return;
  int x = i % no; int t = i / no; int y = t % no; int z = t / no;
  int ni = 2*no;
  float s = 0.f;
#pragma unroll
  for (int a = 0; a < 2; ++a)
#pragma unroll
    for (int b = 0; b < 2; ++b)
#pragma unroll
      for (int c = 0; c < 2; ++c)
        s = fmaf(wr[(a*2+b)*2+c], src[((2*z+a)*ni + (2*y+b))*ni + (2*x+c)], s);
  dst[i] = s;
}

__device__ __forceinline__ float azb_prol(const float* __restrict__ wh, int hs, int s,
    int z, int y, int x, const float* __restrict__ wA) {
  float acc = 0.f;
#pragma unroll
  for (int a = 0; a < 3; ++a) { int zz = z + a - 1; if ((unsigned)zz >= (unsigned)s) continue;
#pragma unroll
    for (int b = 0; b < 3; ++b) { int yy = y + b - 1; if ((unsigned)yy >= (unsigned)s) continue;
#pragma unroll
      for (int c = 0; c < 3; ++c) { int xx = x + c - 1; if ((unsigned)xx >= (unsigned)s) continue;
        acc = fmaf(wA[(a*3+b)*3+c], wh[((zz>>1)*hs + (yy>>1))*hs + (xx>>1)], acc);
      } } }
  return acc;
}

__global__ void __launch_bounds__(512) k_mg_small(
    float* __restrict__ w16, float* __restrict__ r_o,
    const float* __restrict__ rc2,
    const float* __restrict__ wA, const float* __restrict__ wr) {
  __shared__ float r16[4096];
  __shared__ float r8[512];
  __shared__ float r4[64];
  __shared__ float r2[8];
  __shared__ float wa[512];
  __shared__ float wb[64];
  __shared__ float scal[2];
  int tid = threadIdx.x;
  float diag = wA[13];
  float wrl[8];
#pragma unroll
  for (int j = 0; j < 8; ++j) wrl[j] = wr[j];

  for (int j = tid; j < 4096; j += 512) {
    int x = j & 15, y = (j >> 4) & 15, z = j >> 8;
    float s = 0.f;
#pragma unroll
    for (int a = 0; a < 2; ++a)
#pragma unroll
      for (int b = 0; b < 2; ++b)
#pragma unroll
        for (int c = 0; c < 2; ++c)
          s = fmaf(wrl[(a*2+b)*2+c], rc2[((2*z+a)*32 + (2*y+b))*32 + (2*x+c)], s);
    r16[j] = s;
  }
  __syncthreads();
  {
    int j = tid;
    int x = j & 7, y = (j >> 3) & 7, z = j >> 6;
    float s = 0.f;
#pragma unroll
    for (int a = 0; a < 2; ++a)
#pragma unroll
      for (int b = 0; b < 2; ++b)
#pragma unroll
        for (int c = 0; c < 2; ++c)
          s = fmaf(wrl[(a*2+b)*2+c], r16[((2*z+a)*16 + (2*y+b))*16 + (2*x+c)], s);
    r8[j] = s;
  }
  __syncthreads();
  if (tid < 64) {
    int x = tid & 3, y = (tid >> 2) & 3, z = tid >> 4;
    float s = 0.f;
#pragma unroll
    for (int a = 0; a < 2; ++a)
#pragma unroll
      for (int b = 0; b < 2; ++b)
#pragma unroll
        for (int c = 0; c < 2; ++c)
          s = fmaf(wrl[(a*2+b)*2+c], r8[((2*z+a)*8 + (2*y+b))*8 + (2*x+c)], s);
    r4[tid] = s;
  }
  __syncthreads();
  if (tid < 8) {
    int x = tid & 1, y = (tid >> 1) & 1, z = tid >> 2;
    float s = 0.f;
#pragma unroll
    for (int a = 0; a < 2; ++a)
#pragma unroll
      for (int b = 0; b < 2; ++b)
#pragma unroll
        for (int c = 0; c < 2; ++c)
          s = fmaf(wrl[(a*2+b)*2+c], r4[((2*z+a)*4 + (2*y+b))*4 + (2*x+c)], s);
    r2[tid] = s;
  }
  __syncthreads();
  if (tid == 0) {
    float s = 0.f;
#pragma unroll
    for (int j = 0; j < 8; ++j) s = fmaf(wrl[j], r2[j], s);
    scal[0] = s;
    r_o[0] = s;
    scal[1] = s / diag;
  }
  __syncthreads();
  if (tid < 8) {
    int x = tid & 1, y = (tid >> 1) & 1, z = tid >> 2;
    float wp = scal[1];
    float az = azb_prol(&scal[1], 1, 2, z, y, x, wA);
    wa[tid] = wp - az/diag + r2[tid]/diag;
  }
  __syncthreads();
  if (tid < 64) {
    int x = tid & 3, y = (tid >> 2) & 3, z = tid >> 4;
    float wp = wa[((z>>1)*2 + (y>>1))*2 + (x>>1)];
    float az = azb_prol(wa, 2, 4, z, y, x, wA);
    wb[tid] = wp - az/diag + r4[tid]/diag;
  }
  __syncthreads();
  {
    int j = tid;
    int x = j & 7, y = (j >> 3) & 7, z = j >> 6;
    float wp = wb[((z>>1)*4 + (y>>1))*4 + (x>>1)];
    float az = azb_prol(wb, 4, 8, z, y, x, wA);
    wa[j] = wp - az/diag + r8[j]/diag;
  }
  __syncthreads();
  for (int j = tid; j < 4096; j += 512) {
    int x = j & 15, y = (j >> 4) & 15, z = j >> 8;
    float wp = wa[((z>>1)*8 + (y>>1))*8 + (x>>1)];
    float az = azb_prol(wa, 8, 16, z, y, x, wA);
    w16[j] = wp - az/diag + r16[j]/diag;
  }
}

__global__ void __launch_bounds__(256) k_coarse_step(
    float* __restrict__ wout, const float* __restrict__ wh,
    const float* __restrict__ rl, const float* __restrict__ wA, int s) {
  int i = blockIdx.x*256 + threadIdx.x;
  int n3 = s*s*s;
  if (i >= n3) return;
  int x = i % s; int t = i / s; int y = t % s; int z = t / s;
  int hs = s >> 1;
  float diag = wA[13];
  float wp = wh[((z>>1)*hs + (y>>1))*hs + (x>>1)];
  float az = azb_prol(wh, hs, s, z, y, x, wA);
  wout[i] = wp - az/diag + rl[i]/diag;
}

__global__ void __launch_bounds__(256) k_pupd4(
    float* __restrict__ pdst, float* __restrict__ wmgo,
    const float* __restrict__ psrc, const float* __restrict__ rfine,
    const float* __restrict__ w64, const float* __restrict__ wA, int writeWmg) {
  int i4 = blockIdx.x*256 + threadIdx.x;
  if (i4 >= NF/4) return;
  int i = i4*4;
  int x = i & (NN-1); int t = i >> 7; int y = t & (NN-1); int z = t >> 7;
  float rdiag = 1.0f / wA[13];
  float2 w2 = *(const float2*)(w64 + ((size_t)(z>>1)*64 + (y>>1))*64 + (x>>1));
  float4 ps = ((const float4*)psrc)[i4];
  float4 rf = ((const float4*)rfine)[i4];
  float4 o = make_float4(ps.x - w2.x - rf.x*rdiag,
                         ps.y - w2.x - rf.y*rdiag,
                         ps.z - w2.y - rf.z*rdiag,
                         ps.w - w2.y - rf.w*rdiag);
  ((float4*)pdst)[i4] = o;
  if (writeWmg) ((float4*)wmgo)[i4] = make_float4(w2.x, w2.x, w2.y, w2.y);
}

// Final projection (x-quad, plane-major grid).
__global__ void __launch_bounds__(256) k_proj3(
    float* __restrict__ u, float* __restrict__ v, float* __restrict__ w,
    const float* __restrict__ pf, const float* __restrict__ sg,
    const float* __restrict__ wx, const float* __restrict__ wy,
    const float* __restrict__ wz, const float* __restrict__ dtp) {
  int x0 = threadIdx.x * 4;
  int y  = blockIdx.x * 8 + threadIdx.y;   // yband fastest
  int z  = blockIdx.y;                      // z slowest
  bool lo = (x0 == 0), hi = (x0 == NN-4);
  int rb[9]; bool rn[9];
  prep9(z, y, rb, rn);
  float aP[3][4] = {};
  sten_p3(pf, rb, rn, lo, hi, x0, wx, wy, wz, aP);
  float dt = dtp[0];
  int i4 = ((z*NN + y)*NN + x0) >> 2;
  float4 u4 = ((const float4*)u)[i4];
  float4 v4 = ((const float4*)v)[i4];
  float4 w4 = ((const float4*)w)[i4];
  float4 sg4 = ((const float4*)sg)[i4];
  float ua[4] = {u4.x, u4.y, u4.z, u4.w};
  float va[4] = {v4.x, v4.y, v4.z, v4.w};
  float wa[4] = {w4.x, w4.y, w4.z, w4.w};
  float sa[4] = {sg4.x, sg4.y, sg4.z, sg4.w};
  float ou[4], ov[4], ow[4];
#pragma unroll
  for (int k = 0; k < 4; ++k) {
    float d = 1.0f + dt*sa[k];
    ou[k] = (ua[k] - aP[0][k]*dt)/d;
    ov[k] = (va[k] - aP[1][k]*dt)/d;
    ow[k] = (wa[k] - aP[2][k]*dt)/d;
  }
  ((float4*)u)[i4] = make_float4(ou[0], ou[1], ou[2], ou[3]);
  ((float4*)v)[i4] = make_float4(ov[0], ov[1], ov[2], ov[3]);
  ((float4*)w)[i4] = make_float4(ow[0], ow[1], ow[2], ow[3]);
}

// ---------- launch ----------

extern "C" void kernel_launch(void* const* d_in, const int* in_sizes, int n_in,
                              void* d_out, int out_size, void* d_ws, size_t ws_size,
                              hipStream_t stream) {
  const float* values_u = (const float*)d_in[0];
  const float* values_v = (const float*)d_in[1];
  const float* values_w = (const float*)d_in[2];
  const float* values_p = (const float*)d_in[3];
  const float* sigma    = (const float*)d_in[4];
  const float* wx       = (const float*)d_in[5];
  const float* wy       = (const float*)d_in[6];
  const float* wz       = (const float*)d_in[7];
  const float* wd       = (const float*)d_in[8];
  const float* wA       = (const float*)d_in[9];
  const float* wr       = (const float*)d_in[10];
  const float* dtp      = (const float*)d_in[11];

  float* out   = (float*)d_out;
  float* u_o   = out;
  float* v_o   = out + (size_t)NF;
  float* w_o   = out + (size_t)2*NF;
  float* p_o   = out + (size_t)3*NF;
  float* wmg_o = out + (size_t)4*NF;
  float* r_o   = out + (size_t)5*NF;

  float* ws    = (float*)d_ws;
  float* f0    = ws;                     // b_u
  float* f1    = f0 + (size_t)NF;        // b_v
  float* f2    = f1 + (size_t)NF;        // b_w
  float* bws   = f2 + (size_t)NF;        // b
  float* rfine = bws + (size_t)NF;       // A(pp)-b
  float* pbuf  = rfine + (size_t)NF;     // p after iter 0
  float* rc1   = pbuf + (size_t)NF;      // 64^3
  float* rc2   = rc1 + 262144;           // 32^3
  float* w16   = rc2 + 32768;            // 16^3
  float* w32   = w16 + 4096;             // 32^3
  float* w64   = w32 + 32768;            // 64^3

  const int TB = 256;
  dim3 blkS(32, 8, 1);
  dim3 grdS(16, 128, 1);   // yband fastest, z slowest (plane-major dispatch)

  // momentum chain
  k_solid3<<<NF/4/TB, TB, 0, stream>>>(u_o, v_o, w_o, values_u, values_v, values_w, sigma, dtp);
  k_mom3<<<grdS, blkS, 0, stream>>>(f0, f1, f2, u_o, v_o, w_o, u_o, v_o, w_o,
                                    values_p, sigma, wx, wy, wz, wd, dtp, 0.5f);
  k_mom3<<<grdS, blkS, 0, stream>>>(u_o, v_o, w_o, f0, f1, f2, u_o, v_o, w_o,
                                    values_p, sigma, wx, wy, wz, wd, dtp, 1.0f);

  // it 0: fused b + residual + first restriction
  k_bdiv_resres<<<1024, TB, 0, stream>>>(bws, rfine, rc1, u_o, v_o, w_o, values_p,
                                         wx, wy, wz, wA, wr, dtp);
  k_restrict<<<128, TB, 0, stream>>>(rc2, rc1, wr, 32);
  k_mg_small<<<1, 512, 0, stream>>>(w16, r_o, rc2, wA, wr);
  k_coarse_step<<<128, TB, 0, stream>>>(w32, w16, rc2, wA, 32);
  k_coarse_step<<<1024, TB, 0, stream>>>(w64, w32, rc1, wA, 64);
  k_pupd4<<<NF/4/TB, TB, 0, stream>>>(pbuf, wmg_o, values_p, rfine, w64, wA, 0);

  // it 1
  k_resres1<<<1024, TB, 0, stream>>>(rfine, rc1, pbuf, bws, wA, wr);
  k_restrict<<<128, TB, 0, stream>>>(rc2, rc1, wr, 32);
  k_mg_small<<<1, 512, 0, stream>>>(w16, r_o, rc2, wA, wr);
  k_coarse_step<<<128, TB, 0, stream>>>(w32, w16, rc2, wA, 32);
  k_coarse_step<<<1024, TB, 0, stream>>>(w64, w32, rc1, wA, 64);
  k_pupd4<<<NF/4/TB, TB, 0, stream>>>(p_o, wmg_o, pbuf, rfine, w64, wA, 1);

  // final projection
  k_proj3<<<grdS, blkS, 0, stream>>>(u_o, v_o, w_o, p_o, sigma, wx, wy, wz, dtp);
}